// Round 16
// baseline (3032.071 us; speedup 1.0000x reference)
//
#include <hip/hip_runtime.h>
#include <hip/hip_cooperative_groups.h>

namespace cg = cooperative_groups;

#define BB 16
#define NN 2048
#define MM 2048
#define EPSF 1e-9f
#define SKIPT (-135.0f)   // exp2(arg) == 0 below this

typedef float v2f __attribute__((ext_vector_type(2)));
constexpr int CH = 64;    // stream chunk length (2 outputs/thread)
constexpr int NB = 2048;  // logical work-blocks per phase

// levels: j = 7..-1 -> -(4^j), then 0.  coef = level * log2(e)
__constant__ float kCoef[10] = {
    (float)(-16384.0 * 1.4426950408889634),
    (float)(-4096.0  * 1.4426950408889634),
    (float)(-1024.0  * 1.4426950408889634),
    (float)(-256.0   * 1.4426950408889634),
    (float)(-64.0    * 1.4426950408889634),
    (float)(-16.0    * 1.4426950408889634),
    (float)(-4.0     * 1.4426950408889634),
    (float)(-1.0     * 1.4426950408889634),
    (float)(-0.25    * 1.4426950408889634),
    0.0f
};

// ================= phase bodies (R12-verified math; b = logical block) =======

__device__ __forceinline__ void initPhase(int b, int tid,
    const float* __restrict__ xyz1, const float* __restrict__ xyz2,
    float4* __restrict__ P1, float4* __restrict__ P2,
    float* __restrict__ remR0,
    float* __restrict__ stRS, float* __restrict__ stU,
    float* __restrict__ stS, float* __restrict__ stT,
    float* __restrict__ out)
{
    const int t = b * 256 + tid;                  // b < 128 covers BN == BM
    P1[t] = make_float4(xyz1[3*t+0], xyz1[3*t+1], xyz1[3*t+2], 0.0f);
    stRS[t] = 0.0f; stRS[BB*NN + t] = 0.0f;
    stU[t]  = 0.0f; stU[BB*NN + t]  = 0.0f;
    P2[t] = make_float4(xyz2[3*t+0], xyz2[3*t+1], xyz2[3*t+2], 0.0f);
    remR0[t] = 1.0f;
    stS[t] = 0.0f; stS[BB*MM + t] = 0.0f;
    stT[t] = 0.0f; stT[BB*MM + t] = 0.0f;
    if (t < BB) out[t] = 0.0f;
}

__device__ __forceinline__ void rowInitPhase(int b, int tid, float4* sBuf,
    const float4* __restrict__ P1, const float4* __restrict__ P2,
    float* __restrict__ stRSacc, float coef)
{
    const int chunks = MM / CH;                   // 32
    const int bpb = (NN / 512) * chunks;          // 128
    const int batch = b / bpb;
    const int rem   = b % bpb;
    const int rg    = rem / chunks;
    const int ic    = rem % chunks;
    const int t     = tid;

    if (t < CH) sBuf[t] = P2[batch * MM + ic * CH + t];
    __syncthreads();

    const int row0 = batch * NN + rg * 512 + t;
    const int row1 = row0 + 256;
    const float4 p0 = P1[row0];
    const float4 p1 = P1[row1];
    const v2f px = {p0.x, p1.x}, py = {p0.y, p1.y}, pz = {p0.z, p1.z};
    v2f rs = {0.0f, 0.0f};
#pragma unroll 4
    for (int ii = 0; ii < CH; ++ii) {
        const float4 q = sBuf[ii];
        const v2f dx = px - q.x, dy = py - q.y, dz = pz - q.z;
        const v2f g = coef * (dx*dx + dy*dy + dz*dz);
        if (__ballot((g.x > SKIPT) || (g.y > SKIPT))) {
            v2f e;
            e.x = __builtin_amdgcn_exp2f(g.x);
            e.y = __builtin_amdgcn_exp2f(g.y);
            rs += e;
        }
    }
    atomicAdd(&stRSacc[row0], rs.x);
    atomicAdd(&stRSacc[row1], rs.y);
}

template<int MODE, bool SPARSE>
__device__ __forceinline__ void colPhase(int b, int tid, float4* sRow,
    const float4* __restrict__ P1, const float4* __restrict__ P2,
    const float* __restrict__ stRSr, const float* __restrict__ stUr,
    float* __restrict__ stRSz, float* __restrict__ stUz,
    const float* __restrict__ remLr, float* __restrict__ remLw,
    const float* __restrict__ scaler, float* __restrict__ scalew,
    float* __restrict__ stS, float* __restrict__ stT,
    float coef)
{
    const int chunks = NN / CH;                   // 32
    const int bpb = (MM / 512) * chunks;          // 128
    const int batch = b / bpb;
    const int rem   = b % bpb;
    const int cgp   = rem / chunks;
    const int ic    = rem % chunks;
    const int t     = tid;

    if (t < CH) {
        const int gi = batch * NN + ic * CH + t;
        float L;
        if (MODE == 0) L = 1.0f;
        else           L = fmaxf(remLr[gi] - scaler[gi] * stUr[gi], 0.0f);
        remLw[gi] = L;
        const float sc = L / (stRSr[gi] + EPSF);
        scalew[gi] = sc;
        const float4 p = P1[gi];
        sRow[t] = make_float4(p.x, p.y, p.z, sc);
        stRSz[gi] = 0.0f; stUz[gi] = 0.0f;
    }
    __syncthreads();

    const int col0 = batch * MM + cgp * 512 + t;
    const int col1 = col0 + 256;
    const float4 q0 = P2[col0];
    const float4 q1 = P2[col1];
    const v2f qx = {q0.x, q1.x}, qy = {q0.y, q1.y}, qz = {q0.z, q1.z};
    v2f s = {0.0f, 0.0f}, tt = {0.0f, 0.0f};
#pragma unroll 4
    for (int ii = 0; ii < CH; ++ii) {
        const float4 a = sRow[ii];
        const v2f dx = a.x - qx, dy = a.y - qy, dz = a.z - qz;
        const v2f d2 = dx*dx + dy*dy + dz*dz;
        if (SPARSE) {
            const v2f g = coef * d2;
            if (__ballot((g.x > SKIPT) || (g.y > SKIPT))) {
                v2f e;
                e.x = __builtin_amdgcn_exp2f(g.x);
                e.y = __builtin_amdgcn_exp2f(g.y);
                e *= a.w;
                v2f sq;
                sq.x = __builtin_amdgcn_sqrtf(d2.x);
                sq.y = __builtin_amdgcn_sqrtf(d2.y);
                s += e;
                tt += e * sq;
            }
        } else {
            v2f e;
            if (MODE == 2) { e.x = a.w; e.y = a.w; }
            else {
                const v2f g = coef * d2;
                e.x = a.w * __builtin_amdgcn_exp2f(g.x);
                e.y = a.w * __builtin_amdgcn_exp2f(g.y);
            }
            v2f sq;
            sq.x = __builtin_amdgcn_sqrtf(d2.x);
            sq.y = __builtin_amdgcn_sqrtf(d2.y);
            s += e;
            tt += e * sq;
        }
    }
    atomicAdd(&stS[col0], s.x);
    atomicAdd(&stT[col0], tt.x);
    atomicAdd(&stS[col1], s.y);
    atomicAdd(&stT[col1], tt.y);
}

template<int MODE, bool SPARSE>
__device__ __forceinline__ void rowPhase(int b, int tid, float4* sCol, float* sPc,
    const float4* __restrict__ P1, const float4* __restrict__ P2,
    const float* __restrict__ stSr, const float* __restrict__ stTr,
    float* __restrict__ stSz, float* __restrict__ stTz,
    const float* __restrict__ remRr, float* __restrict__ remRw,
    float* __restrict__ stRS, float* __restrict__ stU,
    float* __restrict__ out,
    float coefP, float coefN)
{
    const int chunks = MM / CH;                   // 32
    const int bpb = (NN / 512) * chunks;          // 128
    const int batch = b / bpb;
    const int rem   = b % bpb;
    const int rg    = rem / chunks;
    const int ic    = rem % chunks;
    const int t     = tid;

    float c = 0.0f;
    if (t < CH) {
        const int gl = batch * MM + ic * CH + t;
        const float R  = remRr[gl];
        const float s  = stSr[gl];
        const float t2 = stTr[gl];
        const float sumr = s * R;
        const float cons = fminf(R / (sumr + EPSF), 1.0f);
        const float pcol = R * cons;
        const float Rn   = fmaxf(R - sumr * cons, 0.0f);
        remRw[gl] = Rn;
        const float4 p = P2[gl];
        sCol[t] = make_float4(p.x, p.y, p.z, Rn);
        sPc[t]  = pcol;
        stSz[gl] = 0.0f; stTz[gl] = 0.0f;
        if (rg == 0) c = pcol * t2;
    }
    if (rg == 0) {
#pragma unroll
        for (int off = 32; off > 0; off >>= 1) c += __shfl_xor(c, off, 64);
        if (t < CH && (t & 63) == 0) atomicAdd(out + batch, c);
    }
    __syncthreads();

    const int row0 = batch * NN + rg * 512 + t;
    const int row1 = row0 + 256;
    const float4 p0 = P1[row0];
    const float4 p1 = P1[row1];
    const v2f px = {p0.x, p1.x}, py = {p0.y, p1.y}, pz = {p0.z, p1.z};
    v2f rs = {0.0f, 0.0f}, u = {0.0f, 0.0f};
#pragma unroll 4
    for (int ii = 0; ii < CH; ++ii) {
        const float4 q = sCol[ii];
        const float pc = sPc[ii];
        const v2f dx = px - q.x, dy = py - q.y, dz = pz - q.z;
        const v2f d2 = dx*dx + dy*dy + dz*dz;
        if (MODE == 1) {
            const v2f g = coefN * d2;
            if (SPARSE) {
                if (__ballot((g.x > SKIPT) || (g.y > SKIPT))) {
                    v2f en;
                    en.x = __builtin_amdgcn_exp2f(g.x);
                    en.y = __builtin_amdgcn_exp2f(g.y);
                    const v2f e2 = en * en;
                    const v2f e4 = e2 * e2;
                    u  += e4 * pc;                // e_prev = e_next^4
                    rs += en * q.w;
                }
            } else {
                v2f en;
                en.x = __builtin_amdgcn_exp2f(g.x);
                en.y = __builtin_amdgcn_exp2f(g.y);
                const v2f e2 = en * en;
                const v2f e4 = e2 * e2;
                u  += e4 * pc;
                rs += en * q.w;
            }
        } else {
            const v2f g = coefP * d2;
            v2f ep;
            ep.x = __builtin_amdgcn_exp2f(g.x);
            ep.y = __builtin_amdgcn_exp2f(g.y);
            u  += ep * pc;
            rs += q.w;                            // e_next = exp(0) = 1
        }
    }
    atomicAdd(&stRS[row0], rs.x);
    atomicAdd(&stU[row0],  u.x);
    atomicAdd(&stRS[row1], rs.y);
    atomicAdd(&stU[row1],  u.y);
}

__device__ __forceinline__ void finPhase(int b, int tid,
    const float* __restrict__ stSr, const float* __restrict__ stTr,
    const float* __restrict__ remRr, float* __restrict__ out)
{
    const int idx = b * 256 + tid;
    const int batch = idx / MM;
    const float R = remRr[idx];
    const float sumr = stSr[idx] * R;
    const float cons = fminf(R / (sumr + EPSF), 1.0f);
    float c = R * cons * stTr[idx];
#pragma unroll
    for (int off = 32; off > 0; off >>= 1) c += __shfl_xor(c, off, 64);
    if ((tid & 63) == 0) atomicAdd(out + batch, c);
}

// ================= standalone fallback kernels (R12 structure) ===============

__global__ __launch_bounds__(256) void init_kernelF(
    const float* xyz1, const float* xyz2, float4* P1, float4* P2,
    float* remR0, float* stRS, float* stU, float* stS, float* stT, float* out)
{ initPhase(blockIdx.x, threadIdx.x, xyz1, xyz2, P1, P2, remR0, stRS, stU, stS, stT, out); }

__global__ __launch_bounds__(256) void rowInitF(
    const float4* P1, const float4* P2, float* stRSacc, float coef)
{ __shared__ float4 sBuf[CH];
  rowInitPhase(blockIdx.x, threadIdx.x, sBuf, P1, P2, stRSacc, coef); }

template<int MODE, bool SPARSE>
__global__ __launch_bounds__(256) void colF(
    const float4* P1, const float4* P2,
    const float* stRSr, const float* stUr, float* stRSz, float* stUz,
    const float* remLr, float* remLw, const float* scaler, float* scalew,
    float* stS, float* stT, float coef)
{ __shared__ float4 sRow[CH];
  colPhase<MODE, SPARSE>(blockIdx.x, threadIdx.x, sRow, P1, P2,
      stRSr, stUr, stRSz, stUz, remLr, remLw, scaler, scalew, stS, stT, coef); }

template<int MODE, bool SPARSE>
__global__ __launch_bounds__(256) void rowF(
    const float4* P1, const float4* P2,
    const float* stSr, const float* stTr, float* stSz, float* stTz,
    const float* remRr, float* remRw, float* stRS, float* stU,
    float* out, float coefP, float coefN)
{ __shared__ float4 sCol[CH]; __shared__ float sPc[CH];
  rowPhase<MODE, SPARSE>(blockIdx.x, threadIdx.x, sCol, sPc, P1, P2,
      stSr, stTr, stSz, stTz, remRr, remRw, stRS, stU, out, coefP, coefN); }

__global__ __launch_bounds__(256) void finF(
    const float* stSr, const float* stTr, const float* remRr, float* out)
{ finPhase(blockIdx.x, threadIdx.x, stSr, stTr, remRr, out); }

// ================= persistent cooperative kernel (block-stride) ==============

__global__ __launch_bounds__(256, 8) void persistK(
    const float* xyz1, const float* xyz2,
    float4* P1, float4* P2,
    float* remL, float* scale, float* remR,
    float* stRS, float* stU, float* stS, float* stT,
    float* out)
{
    __shared__ float4 sBuf[CH];
    __shared__ float  sPc[CH];
    cg::grid_group g = cg::this_grid();
    const int tid = threadIdx.x;
    const int gsz = gridDim.x;
    const int BN = BB * NN, BM = BB * MM;

    for (int b = blockIdx.x; b < 128; b += gsz)
        initPhase(b, tid, xyz1, xyz2, P1, P2, remR, stRS, stU, stS, stT, out);
    g.sync();

    for (int b = blockIdx.x; b < NB; b += gsz) {
        rowInitPhase(b, tid, sBuf, P1, P2, stRS + 1 * BN, kCoef[0]);
        __syncthreads();
    }
    g.sync();

    for (int j = 0; j < 10; ++j) {
        const int p = j & 1, q = 1 - p;
        for (int b = blockIdx.x; b < NB; b += gsz) {
            if (j == 0)
                colPhase<0, true>(b, tid, sBuf, P1, P2,
                    stRS + q*BN, stU + q*BN, stRS + p*BN, stU + p*BN,
                    remL + p*BN, remL + q*BN, scale + p*BN, scale + q*BN,
                    stS + p*BM, stT + p*BM, kCoef[0]);
            else if (j <= 3)
                colPhase<1, true>(b, tid, sBuf, P1, P2,
                    stRS + q*BN, stU + q*BN, stRS + p*BN, stU + p*BN,
                    remL + p*BN, remL + q*BN, scale + p*BN, scale + q*BN,
                    stS + p*BM, stT + p*BM, kCoef[j]);
            else if (j == 9)
                colPhase<2, false>(b, tid, sBuf, P1, P2,
                    stRS + q*BN, stU + q*BN, stRS + p*BN, stU + p*BN,
                    remL + p*BN, remL + q*BN, scale + p*BN, scale + q*BN,
                    stS + p*BM, stT + p*BM, kCoef[9]);
            else
                colPhase<1, false>(b, tid, sBuf, P1, P2,
                    stRS + q*BN, stU + q*BN, stRS + p*BN, stU + p*BN,
                    remL + p*BN, remL + q*BN, scale + p*BN, scale + q*BN,
                    stS + p*BM, stT + p*BM, kCoef[j]);
            __syncthreads();
        }
        g.sync();

        if (j < 9) {
            for (int b = blockIdx.x; b < NB; b += gsz) {
                if (j <= 2)
                    rowPhase<1, true>(b, tid, sBuf, sPc, P1, P2,
                        stS + p*BM, stT + p*BM, stS + q*BM, stT + q*BM,
                        remR + p*BM, remR + q*BM,
                        stRS + p*BN, stU + p*BN, out, kCoef[j], kCoef[j+1]);
                else if (j < 8)
                    rowPhase<1, false>(b, tid, sBuf, sPc, P1, P2,
                        stS + p*BM, stT + p*BM, stS + q*BM, stT + q*BM,
                        remR + p*BM, remR + q*BM,
                        stRS + p*BN, stU + p*BN, out, kCoef[j], kCoef[j+1]);
                else
                    rowPhase<2, false>(b, tid, sBuf, sPc, P1, P2,
                        stS + p*BM, stT + p*BM, stS + q*BM, stT + q*BM,
                        remR + p*BM, remR + q*BM,
                        stRS + p*BN, stU + p*BN, out, kCoef[8], 0.0f);
                __syncthreads();
            }
            g.sync();
        }
    }

    for (int b = blockIdx.x; b < 128; b += gsz)
        finPhase(b, tid, stS + 1*BM, stT + 1*BM, remR + 1*BM, out);
}

// ================= launcher ==================================================

extern "C" void kernel_launch(void* const* d_in, const int* in_sizes, int n_in,
                              void* d_out, int out_size, void* d_ws, size_t ws_size,
                              hipStream_t stream)
{
    const float* xyz1 = (const float*)d_in[0];
    const float* xyz2 = (const float*)d_in[1];
    float* out = (float*)d_out;

    const int BN = BB * NN, BM = BB * MM;
    float4* P1 = (float4*)d_ws;
    float4* P2 = P1 + BN;
    float* remL  = (float*)(P2 + BM);       // [2][BN]
    float* scale = remL + 2 * BN;           // [2][BN]
    float* remR  = scale + 2 * BN;          // [2][BM]
    float* stRS  = remR + 2 * BM;           // [2][BN]
    float* stU   = stRS + 2 * BN;           // [2][BN]
    float* stS   = stU + 2 * BN;            // [2][BM]
    float* stT   = stS + 2 * BM;            // [2][BM]

    // coefs for fallback path
    float coef[10];
    const double lv[10] = {-16384.0, -4096.0, -1024.0, -256.0, -64.0,
                           -16.0, -4.0, -1.0, -0.25, 0.0};
    for (int i = 0; i < 10; ++i) coef[i] = (float)(lv[i] * 1.4426950408889634);

    // ---- try cooperative path, occupancy-sized ----
    bool coop = false;
    int coopAttr = 0;
    if (hipDeviceGetAttribute(&coopAttr, hipDeviceAttributeCooperativeLaunch, 0)
            == hipSuccess && coopAttr) {
        int maxB = 0;
        if (hipOccupancyMaxActiveBlocksPerMultiprocessor(
                &maxB, (const void*)persistK, 256, 0) == hipSuccess && maxB > 0) {
            int grid = maxB * 256;              // 256 CUs on MI355X
            if (grid > NB) grid = NB;
            void* args[] = {
                (void*)&xyz1, (void*)&xyz2, (void*)&P1, (void*)&P2,
                (void*)&remL, (void*)&scale, (void*)&remR,
                (void*)&stRS, (void*)&stU, (void*)&stS, (void*)&stT, (void*)&out
            };
            if (hipLaunchCooperativeKernel((const void*)persistK, dim3(grid),
                                           dim3(256), args, 0, stream)
                    == hipSuccess)
                coop = true;
        }
    }
    if (coop) return;

    // ---- fallback: verified R12 multi-kernel sequence ----
    dim3 grid(NB), fgrid(128), blk(256);

    init_kernelF<<<fgrid, blk, 0, stream>>>(xyz1, xyz2, P1, P2, remR,
                                            stRS, stU, stS, stT, out);
    rowInitF<<<grid, blk, 0, stream>>>(P1, P2, stRS + 1 * BN, coef[0]);

    for (int j = 0; j < 10; ++j) {
        const int p = j & 1, q = 1 - p;
        if (j == 0)
            colF<0, true><<<grid, blk, 0, stream>>>(P1, P2,
                stRS + q*BN, stU + q*BN, stRS + p*BN, stU + p*BN,
                remL + p*BN, remL + q*BN, scale + p*BN, scale + q*BN,
                stS + p*BM, stT + p*BM, coef[0]);
        else if (j <= 3)
            colF<1, true><<<grid, blk, 0, stream>>>(P1, P2,
                stRS + q*BN, stU + q*BN, stRS + p*BN, stU + p*BN,
                remL + p*BN, remL + q*BN, scale + p*BN, scale + q*BN,
                stS + p*BM, stT + p*BM, coef[j]);
        else if (j == 9)
            colF<2, false><<<grid, blk, 0, stream>>>(P1, P2,
                stRS + q*BN, stU + q*BN, stRS + p*BN, stU + p*BN,
                remL + p*BN, remL + q*BN, scale + p*BN, scale + q*BN,
                stS + p*BM, stT + p*BM, coef[9]);
        else
            colF<1, false><<<grid, blk, 0, stream>>>(P1, P2,
                stRS + q*BN, stU + q*BN, stRS + p*BN, stU + p*BN,
                remL + p*BN, remL + q*BN, scale + p*BN, scale + q*BN,
                stS + p*BM, stT + p*BM, coef[j]);

        if (j < 9) {
            if (j <= 2)
                rowF<1, true><<<grid, blk, 0, stream>>>(P1, P2,
                    stS + p*BM, stT + p*BM, stS + q*BM, stT + q*BM,
                    remR + p*BM, remR + q*BM,
                    stRS + p*BN, stU + p*BN, out, coef[j], coef[j+1]);
            else if (j < 8)
                rowF<1, false><<<grid, blk, 0, stream>>>(P1, P2,
                    stS + p*BM, stT + p*BM, stS + q*BM, stT + q*BM,
                    remR + p*BM, remR + q*BM,
                    stRS + p*BN, stU + p*BN, out, coef[j], coef[j+1]);
            else
                rowF<2, false><<<grid, blk, 0, stream>>>(P1, P2,
                    stS + p*BM, stT + p*BM, stS + q*BM, stT + q*BM,
                    remR + p*BM, remR + q*BM,
                    stRS + p*BN, stU + p*BN, out, coef[8], 0.0f);
        }
    }
    finF<<<fgrid, blk, 0, stream>>>(stS + 1*BM, stT + 1*BM, remR + 1*BM, out);
}

// Round 17
// 513.355 us; speedup vs baseline: 5.9064x; 5.9064x over previous
//
#include <hip/hip_runtime.h>

#define BB 16
#define NN 2048
#define MM 2048
#define EPSF 1e-9f
#define SKIPT (-135.0f)   // exp2(arg) == 0 below this

typedef float v2f __attribute__((ext_vector_type(2)));

constexpr int CH = 64;     // stream chunk length (2 outputs/thread)
// grid: BB batches x 4 groups(512 own-points) x 32 chunks = 2048 blocks
// Ping-pong parity identical to R8-R12 scheme.

// ---------------- init ----------------
__global__ __launch_bounds__(256) void init_kernel(
    const float* __restrict__ xyz1, const float* __restrict__ xyz2,
    float4* __restrict__ P1, float4* __restrict__ P2,
    float* __restrict__ remR0,
    float* __restrict__ stRS, float* __restrict__ stU,
    float* __restrict__ stS, float* __restrict__ stT,
    float* __restrict__ out)
{
    const int t = blockIdx.x * 256 + threadIdx.x;   // 0 .. BB*NN-1
    if (t < BB * NN) {
        P1[t] = make_float4(xyz1[3*t+0], xyz1[3*t+1], xyz1[3*t+2], 0.0f);
        stRS[t] = 0.0f; stRS[BB*NN + t] = 0.0f;
        stU[t]  = 0.0f; stU[BB*NN + t]  = 0.0f;
    }
    if (t < BB * MM) {
        P2[t] = make_float4(xyz2[3*t+0], xyz2[3*t+1], xyz2[3*t+2], 0.0f);
        remR0[t] = 1.0f;
        stS[t] = 0.0f; stS[BB*MM + t] = 0.0f;
        stT[t] = 0.0f; stT[BB*MM + t] = 0.0f;
    }
    if (t < BB) out[t] = 0.0f;
}

// ---------------- rowInit: stRS[1] += sum_l exp(coef0*d2) (remR=1) ----------------
__global__ __launch_bounds__(256) void rowInit(
    const float4* __restrict__ P1, const float4* __restrict__ P2,
    float* __restrict__ stRSacc, float coef)
{
    __shared__ float4 sCol[CH];
    const int chunks = MM / CH;                   // 32
    const int bpb = (NN / 512) * chunks;          // 128
    const int batch = blockIdx.x / bpb;
    const int rem   = blockIdx.x % bpb;
    const int rg    = rem / chunks;
    const int ic    = rem % chunks;
    const int t     = threadIdx.x;

    if (t < CH) sCol[t] = P2[batch * MM + ic * CH + t];
    __syncthreads();

    const int row0 = batch * NN + rg * 512 + t;
    const int row1 = row0 + 256;
    const float4 p0 = P1[row0];
    const float4 p1 = P1[row1];
    const v2f px = {p0.x, p1.x}, py = {p0.y, p1.y}, pz = {p0.z, p1.z};
    v2f rs = {0.0f, 0.0f};
#pragma unroll 4
    for (int ii = 0; ii < CH; ++ii) {
        const float4 q = sCol[ii];
        const v2f dx = px - q.x, dy = py - q.y, dz = pz - q.z;
        const v2f g = coef * (dx*dx + dy*dy + dz*dz);
        if (__ballot((g.x > SKIPT) || (g.y > SKIPT))) {
            v2f e;
            e.x = __builtin_amdgcn_exp2f(g.x);
            e.y = __builtin_amdgcn_exp2f(g.y);
            rs += e;
        }
    }
    atomicAdd(&stRSacc[row0], rs.x);
    atomicAdd(&stRSacc[row1], rs.y);
}

// ---------------- colK: row-finalize prelude + column-partial stream ----------------
// MODE 0: j==0 (remL=1). MODE 1: general. MODE 2: j==9 (coef==0 -> e=scale).
template<int MODE, bool SPARSE>
__global__ __launch_bounds__(256) void colK(
    const float4* __restrict__ P1, const float4* __restrict__ P2,
    const float* __restrict__ stRSr, const float* __restrict__ stUr,
    float* __restrict__ stRSz, float* __restrict__ stUz,
    const float* __restrict__ remLr, float* __restrict__ remLw,
    const float* __restrict__ scaler, float* __restrict__ scalew,
    float* __restrict__ stS, float* __restrict__ stT,
    float coef)
{
    __shared__ float4 sRow[CH];                   // x1,y1,z1,scale_j
    const int chunks = NN / CH;                   // 32
    const int bpb = (MM / 512) * chunks;          // 128
    const int batch = blockIdx.x / bpb;
    const int rem   = blockIdx.x % bpb;
    const int cg    = rem / chunks;
    const int ic    = rem % chunks;
    const int t     = threadIdx.x;

    // prelude: finalize rows of this chunk (duplicated by 4 cg-blocks; identical values)
    if (t < CH) {
        const int gi = batch * NN + ic * CH + t;
        float L;
        if (MODE == 0) L = 1.0f;
        else           L = fmaxf(remLr[gi] - scaler[gi] * stUr[gi], 0.0f);
        remLw[gi] = L;
        const float sc = L / (stRSr[gi] + EPSF);
        scalew[gi] = sc;
        const float4 p = P1[gi];
        sRow[t] = make_float4(p.x, p.y, p.z, sc);
        stRSz[gi] = 0.0f; stUz[gi] = 0.0f;        // zero next accumulation parity
    }
    __syncthreads();

    const int col0 = batch * MM + cg * 512 + t;
    const int col1 = col0 + 256;
    const float4 q0 = P2[col0];
    const float4 q1 = P2[col1];
    const v2f qx = {q0.x, q1.x}, qy = {q0.y, q1.y}, qz = {q0.z, q1.z};
    v2f s = {0.0f, 0.0f}, tt = {0.0f, 0.0f};
#pragma unroll 4
    for (int ii = 0; ii < CH; ++ii) {
        const float4 a = sRow[ii];
        const v2f dx = a.x - qx, dy = a.y - qy, dz = a.z - qz;
        const v2f d2 = dx*dx + dy*dy + dz*dz;
        if (SPARSE) {
            const v2f g = coef * d2;
            if (__ballot((g.x > SKIPT) || (g.y > SKIPT))) {
                v2f e;
                e.x = __builtin_amdgcn_exp2f(g.x);
                e.y = __builtin_amdgcn_exp2f(g.y);
                e *= a.w;
                v2f sq;
                sq.x = __builtin_amdgcn_sqrtf(d2.x);
                sq.y = __builtin_amdgcn_sqrtf(d2.y);
                s += e;
                tt += e * sq;
            }
        } else {
            v2f e;
            if (MODE == 2) { e.x = a.w; e.y = a.w; }
            else {
                const v2f g = coef * d2;
                e.x = a.w * __builtin_amdgcn_exp2f(g.x);
                e.y = a.w * __builtin_amdgcn_exp2f(g.y);
            }
            v2f sq;
            sq.x = __builtin_amdgcn_sqrtf(d2.x);
            sq.y = __builtin_amdgcn_sqrtf(d2.y);
            s += e;
            tt += e * sq;
        }
    }
    atomicAdd(&stS[col0], s.x);
    atomicAdd(&stT[col0], tt.x);
    atomicAdd(&stS[col1], s.y);
    atomicAdd(&stT[col1], tt.y);
}

// ---------------- rowK: col-finalize prelude + row-partial stream ----------------
// MODE 1: general. MODE 2: j==8 (rs = sum remR_9, u at coefP direct).
template<int MODE, bool SPARSE>
__global__ __launch_bounds__(256) void rowK(
    const float4* __restrict__ P1, const float4* __restrict__ P2,
    const float* __restrict__ stSr, const float* __restrict__ stTr,
    float* __restrict__ stSz, float* __restrict__ stTz,
    const float* __restrict__ remRr, float* __restrict__ remRw,
    float* __restrict__ stRS, float* __restrict__ stU,
    float* __restrict__ out,
    float coefP, float coefN)
{
    __shared__ float4 sCol[CH];                   // x2,y2,z2,remR_{j+1}
    __shared__ float  sPc[CH];                    // Pcol_j
    const int chunks = MM / CH;                   // 32
    const int bpb = (NN / 512) * chunks;          // 128
    const int batch = blockIdx.x / bpb;
    const int rem   = blockIdx.x % bpb;
    const int rg    = rem / chunks;
    const int ic    = rem % chunks;
    const int t     = threadIdx.x;

    // prelude: finalize cols of this chunk (duplicated by 4 rg-blocks; identical values)
    float c = 0.0f;
    if (t < CH) {
        const int gl = batch * MM + ic * CH + t;
        const float R  = remRr[gl];
        const float s  = stSr[gl];
        const float t2 = stTr[gl];
        const float sumr = s * R;
        const float cons = fminf(R / (sumr + EPSF), 1.0f);
        const float pcol = R * cons;
        const float Rn   = fmaxf(R - sumr * cons, 0.0f);
        remRw[gl] = Rn;
        const float4 p = P2[gl];
        sCol[t] = make_float4(p.x, p.y, p.z, Rn);
        sPc[t]  = pcol;
        stSz[gl] = 0.0f; stTz[gl] = 0.0f;         // zero next accumulation parity
        if (rg == 0) c = pcol * t2;               // cost contribution (once per chunk)
    }
    if (rg == 0) {
#pragma unroll
        for (int off = 32; off > 0; off >>= 1) c += __shfl_xor(c, off, 64);
        if (t < CH && (t & 63) == 0) atomicAdd(out + batch, c);
    }
    __syncthreads();

    const int row0 = batch * NN + rg * 512 + t;
    const int row1 = row0 + 256;
    const float4 p0 = P1[row0];
    const float4 p1 = P1[row1];
    const v2f px = {p0.x, p1.x}, py = {p0.y, p1.y}, pz = {p0.z, p1.z};
    v2f rs = {0.0f, 0.0f}, u = {0.0f, 0.0f};
#pragma unroll 4
    for (int ii = 0; ii < CH; ++ii) {
        const float4 q = sCol[ii];
        const float pc = sPc[ii];
        const v2f dx = px - q.x, dy = py - q.y, dz = pz - q.z;
        const v2f d2 = dx*dx + dy*dy + dz*dz;
        if (MODE == 1) {
            const v2f g = coefN * d2;
            if (SPARSE) {
                if (__ballot((g.x > SKIPT) || (g.y > SKIPT))) {
                    v2f en;
                    en.x = __builtin_amdgcn_exp2f(g.x);
                    en.y = __builtin_amdgcn_exp2f(g.y);
                    const v2f e2 = en * en;
                    const v2f e4 = e2 * e2;
                    u  += e4 * pc;                // e_prev = e_next^4
                    rs += en * q.w;
                }
            } else {
                v2f en;
                en.x = __builtin_amdgcn_exp2f(g.x);
                en.y = __builtin_amdgcn_exp2f(g.y);
                const v2f e2 = en * en;
                const v2f e4 = e2 * e2;
                u  += e4 * pc;
                rs += en * q.w;
            }
        } else {
            const v2f g = coefP * d2;
            v2f ep;
            ep.x = __builtin_amdgcn_exp2f(g.x);
            ep.y = __builtin_amdgcn_exp2f(g.y);
            u  += ep * pc;
            rs += q.w;                            // e_next = exp(0) = 1
        }
    }
    atomicAdd(&stRS[row0], rs.x);
    atomicAdd(&stU[row0], u.x);
    atomicAdd(&stRS[row1], rs.y);
    atomicAdd(&stU[row1], u.y);
}

// ---------------- finCost: cost for level 9 (no state updates) ----------------
__global__ __launch_bounds__(256) void finCost(
    const float* __restrict__ stSr, const float* __restrict__ stTr,
    const float* __restrict__ remRr, float* __restrict__ out)
{
    const int idx = blockIdx.x * 256 + threadIdx.x;
    const int batch = idx / MM;
    const float R = remRr[idx];
    const float sumr = stSr[idx] * R;
    const float cons = fminf(R / (sumr + EPSF), 1.0f);
    float c = R * cons * stTr[idx];
#pragma unroll
    for (int off = 32; off > 0; off >>= 1) c += __shfl_xor(c, off, 64);
    if ((threadIdx.x & 63) == 0) atomicAdd(out + batch, c);
}

extern "C" void kernel_launch(void* const* d_in, const int* in_sizes, int n_in,
                              void* d_out, int out_size, void* d_ws, size_t ws_size,
                              hipStream_t stream)
{
    const float* xyz1 = (const float*)d_in[0];
    const float* xyz2 = (const float*)d_in[1];
    float* out = (float*)d_out;

    const int BN = BB * NN, BM = BB * MM;
    float4* P1 = (float4*)d_ws;
    float4* P2 = P1 + BN;
    float* remL  = (float*)(P2 + BM);       // [2][BN]
    float* scale = remL + 2 * BN;           // [2][BN]
    float* remR  = scale + 2 * BN;          // [2][BM]
    float* stRS  = remR + 2 * BM;           // [2][BN]
    float* stU   = stRS + 2 * BN;           // [2][BN]
    float* stS   = stU + 2 * BN;            // [2][BM]
    float* stT   = stS + 2 * BM;            // [2][BM]

    init_kernel<<<dim3(BN / 256), dim3(256), 0, stream>>>(
        xyz1, xyz2, P1, P2, remR, stRS, stU, stS, stT, out);

    // levels: j = 7..-1 -> -(4^j), then 0.  coef = level * log2(e)
    float coef[10];
    const double lv[10] = {-16384.0, -4096.0, -1024.0, -256.0, -64.0,
                           -16.0, -4.0, -1.0, -0.25, 0.0};
    for (int i = 0; i < 10; ++i) coef[i] = (float)(lv[i] * 1.4426950408889634);

    dim3 grid(BB * 4 * (NN / CH));          // 16*4*32 = 2048
    dim3 fgrid(BM / 256);                   // 128
    dim3 blk(256);

    rowInit<<<grid, blk, 0, stream>>>(P1, P2, stRS + 1 * BN, coef[0]);

    for (int j = 0; j < 10; ++j) {
        const int p = j & 1, q = 1 - p;
        if (j == 0)
            colK<0, true><<<grid, blk, 0, stream>>>(P1, P2,
                stRS + q*BN, stU + q*BN, stRS + p*BN, stU + p*BN,
                remL + p*BN, remL + q*BN, scale + p*BN, scale + q*BN,
                stS + p*BM, stT + p*BM, coef[0]);
        else if (j <= 3)
            colK<1, true><<<grid, blk, 0, stream>>>(P1, P2,
                stRS + q*BN, stU + q*BN, stRS + p*BN, stU + p*BN,
                remL + p*BN, remL + q*BN, scale + p*BN, scale + q*BN,
                stS + p*BM, stT + p*BM, coef[j]);
        else if (j == 9)
            colK<2, false><<<grid, blk, 0, stream>>>(P1, P2,
                stRS + q*BN, stU + q*BN, stRS + p*BN, stU + p*BN,
                remL + p*BN, remL + q*BN, scale + p*BN, scale + q*BN,
                stS + p*BM, stT + p*BM, coef[9]);
        else
            colK<1, false><<<grid, blk, 0, stream>>>(P1, P2,
                stRS + q*BN, stU + q*BN, stRS + p*BN, stU + p*BN,
                remL + p*BN, remL + q*BN, scale + p*BN, scale + q*BN,
                stS + p*BM, stT + p*BM, coef[j]);

        if (j < 9) {
            if (j <= 2)
                rowK<1, true><<<grid, blk, 0, stream>>>(P1, P2,
                    stS + p*BM, stT + p*BM, stS + q*BM, stT + q*BM,
                    remR + p*BM, remR + q*BM,
                    stRS + p*BN, stU + p*BN, out, coef[j], coef[j+1]);
            else if (j < 8)
                rowK<1, false><<<grid, blk, 0, stream>>>(P1, P2,
                    stS + p*BM, stT + p*BM, stS + q*BM, stT + q*BM,
                    remR + p*BM, remR + q*BM,
                    stRS + p*BN, stU + p*BN, out, coef[j], coef[j+1]);
            else
                rowK<2, false><<<grid, blk, 0, stream>>>(P1, P2,
                    stS + p*BM, stT + p*BM, stS + q*BM, stT + q*BM,
                    remR + p*BM, remR + q*BM,
                    stRS + p*BN, stU + p*BN, out, coef[8], 0.0f);
        }
    }
    // level 9 cost: stS/stT parity 1, remR parity 1
    finCost<<<fgrid, blk, 0, stream>>>(stS + 1*BM, stT + 1*BM, remR + 1*BM, out);
}